// Round 5
// baseline (4686.889 us; speedup 1.0000x reference)
//
#include <hip/hip_runtime.h>

typedef unsigned short u16;
typedef unsigned int u32;
typedef __attribute__((ext_vector_type(8))) short short8;
typedef __attribute__((ext_vector_type(4))) float float4v;
typedef __attribute__((ext_vector_type(2))) float float2v;

#define B_SZ 4096
#define T_SZ 32
#define XD 256
#define HD 256
#define ZD 256
#define GD 128
#define YD 2

#define BM 32          // batch rows per block
#define NW 8           // waves per block (512 threads) -> 2 waves/SIMD -> 256 regs/wave

// bf16 weight fragment buffer layout in d_ws (elem offsets) — frag-contiguous:
// addr = base + ((ntile*KT + kt)<<9) + lane*8 + j ; lane=(n&15)|(((k>>3)&3)<<4), j=k&7
#define W1_OFF 0              // [Wr|Wu]  N=512 (32 ntiles), KT=24
#define W2_OFF 393216         // Wh       N=256 (16 ntiles), KT=24
#define W3_OFF 589824         // [Wzp|Wzq] N=512 (32 ntiles), KT=17 (K=544: x,h,y+pad; Wzp kt16 = zeros)
#define W4_OFF 868352         // [Wpm|Wps|Wqm|Wqs] N=1024 (64 ntiles), KT=8
#define WG_OFF 1130496        // Wg       N=128 (8 ntiles),  KT=24
#define WTOT   1228800

#define YTOT  (B_SZ*T_SZ*YD)        // 262144
#define KLTOT (B_SZ*T_SZ)           // 131072

#define UST 264    // u_bf row stride (bf16) inside a3s alias

__device__ __forceinline__ u16 f2bf(float f) {
    u32 u = __float_as_uint(f);
    u32 r = (u + 0x7fffu + ((u >> 16) & 1u)) >> 16;
    return (u16)r;
}
__device__ __forceinline__ float bf2f(u16 h) {
    return __uint_as_float(((u32)h) << 16);
}
__device__ __forceinline__ float tanh_f(float x) {
    float e = __expf(2.f * x);
    return 1.f - 2.f / (e + 1.f);
}
__device__ __forceinline__ float sigm_f(float x) {
    return 1.f / (1.f + __expf(-x));
}

// a_ga: 48 tiles ((r>>4)*24+kt) of 512 elems, frag-contiguous. rows 0..31, k 0..767
__device__ __forceinline__ int aga_off(int r, int k) {
    return (((r >> 4) * 24 + (k >> 5)) << 9) + ((((k >> 3) & 3) * 16 + (r & 15)) << 3) + (k & 7);
}
// a3s (P|Q, 32 rows x 256 cols each): tiles ((pq*2+mt)*8+kt)
__device__ __forceinline__ int a3s_off(int r, int k, int pq) {
    return (((pq * 2 + (r >> 4)) * 8 + (k >> 5)) << 9) + ((((k >> 3) & 3) * 16 + (r & 15)) << 3) + (k & 7);
}

#define MFMA(a, b, c) __builtin_amdgcn_mfma_f32_16x16x32_bf16(a, b, c, 0, 0, 0)

// ---------------------------------------------------------------------------
__global__ void prep_weights(const float* __restrict__ Wr, const float* __restrict__ Wu,
                             const float* __restrict__ Wh, const float* __restrict__ Wzp,
                             const float* __restrict__ Wzq, const float* __restrict__ Wpm,
                             const float* __restrict__ Wps, const float* __restrict__ Wqm,
                             const float* __restrict__ Wqs, const float* __restrict__ Wg,
                             u16* __restrict__ wts)
{
    int o = blockIdx.x * 256 + threadIdx.x;
    if (o >= WTOT) return;
    int mat, w, KT;
    if (o < W2_OFF)      { mat = 0; w = o;          KT = 24; }
    else if (o < W3_OFF) { mat = 1; w = o - W2_OFF; KT = 24; }
    else if (o < W4_OFF) { mat = 2; w = o - W3_OFF; KT = 17; }
    else if (o < WG_OFF) { mat = 3; w = o - W4_OFF; KT = 8;  }
    else                 { mat = 4; w = o - WG_OFF; KT = 24; }
    int nt  = w / (KT * 512);
    int rem = w - nt * (KT * 512);
    int kt  = rem >> 9;
    int q   = rem & 511;
    int lane = q >> 3, j = q & 7;
    int n = (nt << 4) | (lane & 15);
    int k = (kt << 5) + ((lane >> 4) << 3) + j;
    float v = 0.f;
    switch (mat) {
        case 0: v = (n < 256) ? Wr[k * 256 + n] : Wu[k * 256 + (n - 256)]; break;
        case 1: v = Wh[k * 256 + n]; break;
        case 2: v = (n < 256) ? (k < 512 ? Wzp[k * 256 + n] : 0.f)
                              : (k < 514 ? Wzq[k * 256 + (n - 256)] : 0.f); break;
        case 3: { int sel = n >> 8; int nn = n & 255;
                  const float* s = (sel == 0) ? Wpm : (sel == 1) ? Wps : (sel == 2) ? Wqm : Wqs;
                  v = s[k * 256 + nn]; } break;
        default: v = Wg[k * 128 + n]; break;
    }
    wts[o] = f2bf(v);
}

// ---------------------------------------------------------------------------
__global__ __launch_bounds__(512, 2) void vrnn_all(
    const float* __restrict__ x,   const float* __restrict__ y_ph,
    const int*   __restrict__ Tph, const float* __restrict__ h0,
    const float* __restrict__ z0,  const float* __restrict__ eps,
    const float* __restrict__ br,  const float* __restrict__ bu,
    const float* __restrict__ bh,  const float* __restrict__ bzp,
    const float* __restrict__ bpm, const float* __restrict__ bps,
    const float* __restrict__ bzq, const float* __restrict__ bqm,
    const float* __restrict__ bqs, const float* __restrict__ bg,
    const float* __restrict__ by,  const float* __restrict__ Wy,
    const u16*   __restrict__ wts, float* __restrict__ out)
{
    __shared__ __align__(16) u16   a_ga[48 * 512];   // 49.2 KB  [x|h|z] frag tiles (32 rows)
    __shared__ __align__(16) u16   a3s[32 * 512];    // 32.8 KB  union: P/Q frags | u_bf (32*264)
    __shared__ float part[NW * BM * 2];              // 2 KB  y-head partials
    __shared__ float kl_acc[BM];
    __shared__ int   tph_s[BM];

    const int tid  = threadIdx.x;
    const int wv   = tid >> 6;          // 0..7
    const int lane = tid & 63;
    const int quad = lane >> 4;
    const int l15  = lane & 15;
    const int b0   = blockIdx.x * BM;

    // --- per-lane register-resident biases / Wy ---
    const int c1b = 64 * wv + l15;      // stage1 col base (4 ntiles/wave)
    float bs1[4];
#pragma unroll
    for (int nt = 0; nt < 4; ++nt) {
        int c = c1b + nt * 16;
        bs1[nt] = (c < 256) ? br[c] : bu[c - 256];
    }
    const int c2a = 32 * wv + l15;      // stage2/3/4 cols (2 coltiles/wave)
    const int c2b = c2a + 16;
    const float bh_a  = bh[c2a],  bh_b  = bh[c2b];
    const float bzp_a = bzp[c2a], bzp_b = bzp[c2b];
    const float bzq_a = bzq[c2a], bzq_b = bzq[c2b];
    const float bpm_a = bpm[c2a], bpm_b = bpm[c2b];
    const float bps_a = bps[c2a], bps_b = bps[c2b];
    const float bqm_a = bqm[c2a], bqm_b = bqm[c2b];
    const float bqs_a = bqs[c2a], bqs_b = bqs[c2b];
    const int c5  = 16 * wv + l15;      // stage5 col (1 coltile/wave)
    const float bg_r = bg[c5];
    const float wy0 = Wy[c5 * 2], wy1 = Wy[c5 * 2 + 1];
    const float by0 = by[0], by1 = by[1];

    if (tid < BM) tph_s[tid] = Tph[b0 + tid];

    // --- fp32 recurrent h in registers: rows mt*16+quad*4+i, cols c2a/c2b ---
    float h32r[2][2][4];
#pragma unroll
    for (int ct = 0; ct < 2; ++ct)
#pragma unroll
        for (int mt = 0; mt < 2; ++mt)
#pragma unroll
            for (int i = 0; i < 4; ++i) {
                int row = mt * 16 + quad * 4 + i;
                int c = ct ? c2b : c2a;
                h32r[ct][mt][i] = __builtin_nontemporal_load(&h0[(size_t)(b0 + row) * HD + c]);
            }

    const int sr  = tid >> 4;          // staging row 0..31
    const int scc = (tid & 15) * 16;   // staging col base (16 cols per thread)

    // --- x(t=0) prefetch + bf16 h,z staging into a_ga ---
    float4v xn[4];
    {
        const float* xp = &x[((size_t)(b0 + sr) * T_SZ + 0) * XD + scc];
#pragma unroll
        for (int q = 0; q < 4; ++q) xn[q] = __builtin_nontemporal_load((const float4v*)(xp + q * 4));

        const float* hp = &h0[(size_t)(b0 + sr) * HD + scc];
        const float* zp = &z0[(size_t)(b0 + sr) * ZD + scc];
        float4v hv[4], zv[4];
#pragma unroll
        for (int q = 0; q < 4; ++q) {
            hv[q] = __builtin_nontemporal_load((const float4v*)(hp + q * 4));
            zv[q] = __builtin_nontemporal_load((const float4v*)(zp + q * 4));
        }
        short8 hs0, hs1, zs0, zs1;
#pragma unroll
        for (int j = 0; j < 4; ++j) {
            hs0[j] = (short)f2bf(hv[0][j]); hs0[4 + j] = (short)f2bf(hv[1][j]);
            hs1[j] = (short)f2bf(hv[2][j]); hs1[4 + j] = (short)f2bf(hv[3][j]);
            zs0[j] = (short)f2bf(zv[0][j]); zs0[4 + j] = (short)f2bf(zv[1][j]);
            zs1[j] = (short)f2bf(zv[2][j]); zs1[4 + j] = (short)f2bf(zv[3][j]);
        }
        *(short8*)&a_ga[aga_off(sr, 256 + scc)]     = hs0;
        *(short8*)&a_ga[aga_off(sr, 256 + scc + 8)] = hs1;
        *(short8*)&a_ga[aga_off(sr, 512 + scc)]     = zs0;
        *(short8*)&a_ga[aga_off(sr, 512 + scc + 8)] = zs1;
    }
    __syncthreads();

    const float4v zero4 = {0.f, 0.f, 0.f, 0.f};
    float yA0 = 0.f, yA1 = 0.f, yB0 = 0.f, yB1 = 0.f, klA = 0.f, klB = 0.f;

    for (int t = 0; t < T_SZ; ++t) {
        // --- stage x_t into a_ga cols [0,256) from prefetched registers ---
        {
            short8 s0, s1;
#pragma unroll
            for (int j = 0; j < 4; ++j) {
                s0[j] = (short)f2bf(xn[0][j]); s0[4 + j] = (short)f2bf(xn[1][j]);
                s1[j] = (short)f2bf(xn[2][j]); s1[4 + j] = (short)f2bf(xn[3][j]);
            }
            *(short8*)&a_ga[aga_off(sr, scc)]     = s0;
            *(short8*)&a_ga[aga_off(sr, scc + 8)] = s1;
        }
        __syncthreads();   // bar1

        // ============ stage 1: [r|u] = sigmoid([x,h,z] @ W1), 4 ntiles/wave ============
        {
            const u16* pB[4];
#pragma unroll
            for (int nt = 0; nt < 4; ++nt)
                pB[nt] = wts + W1_OFF + (((4 * wv + nt) * 24) << 9) + lane * 8;
            short8 rg[4][4];
#pragma unroll
            for (int d = 0; d < 4; ++d)
#pragma unroll
                for (int nt = 0; nt < 4; ++nt)
                    rg[nt][d] = *(const short8*)(pB[nt] + (d << 9));
            float4v ac[4][2];
#pragma unroll
            for (int nt = 0; nt < 4; ++nt) { ac[nt][0] = zero4; ac[nt][1] = zero4; }
#pragma unroll
            for (int kt = 0; kt < 24; ++kt) {
                short8 aF0 = *(const short8*)&a_ga[(kt << 9) + lane * 8];
                short8 aF1 = *(const short8*)&a_ga[((24 + kt) << 9) + lane * 8];
                short8 b0c = rg[0][kt & 3], b1c = rg[1][kt & 3];
                short8 b2c = rg[2][kt & 3], b3c = rg[3][kt & 3];
                if (kt + 4 < 24) {
#pragma unroll
                    for (int nt = 0; nt < 4; ++nt)
                        rg[nt][kt & 3] = *(const short8*)(pB[nt] + ((kt + 4) << 9));
                }
                ac[0][0] = MFMA(aF0, b0c, ac[0][0]); ac[0][1] = MFMA(aF1, b0c, ac[0][1]);
                ac[1][0] = MFMA(aF0, b1c, ac[1][0]); ac[1][1] = MFMA(aF1, b1c, ac[1][1]);
                ac[2][0] = MFMA(aF0, b2c, ac[2][0]); ac[2][1] = MFMA(aF1, b2c, ac[2][1]);
                ac[3][0] = MFMA(aF0, b3c, ac[3][0]); ac[3][1] = MFMA(aF1, b3c, ac[3][1]);
            }
            __syncthreads();   // bar2: all a_ga reads done before rh overwrite
            // epilogue — branch is wave-uniform (wv<4 -> r-part, wv>=4 -> u-part)
#pragma unroll
            for (int nt = 0; nt < 4; ++nt) {
                int c = c1b + nt * 16;
#pragma unroll
                for (int mt = 0; mt < 2; ++mt)
#pragma unroll
                    for (int i = 0; i < 4; ++i) {
                        int row = mt * 16 + quad * 4 + i;
                        float s = sigm_f(ac[nt][mt][i] + bs1[nt]);
                        if (c < 256) {
                            int o = aga_off(row, 256 + c);
                            a_ga[o] = f2bf(s * bf2f(a_ga[o]));
                        } else {
                            a3s[row * UST + (c - 256)] = f2bf(s);   // u_bf alias
                        }
                    }
            }
            __syncthreads();   // bar3
        }

        // ============ stage 2: h_tilde = tanh([x,rh,z] @ Wh); h update ============
        {
            const u16* pB[2];
            pB[0] = wts + W2_OFF + (((2 * wv    ) * 24) << 9) + lane * 8;
            pB[1] = wts + W2_OFF + (((2 * wv + 1) * 24) << 9) + lane * 8;
            short8 rg[2][4];
#pragma unroll
            for (int d = 0; d < 4; ++d) {
                rg[0][d] = *(const short8*)(pB[0] + (d << 9));
                rg[1][d] = *(const short8*)(pB[1] + (d << 9));
            }
            float4v ac[2][2];
            ac[0][0] = zero4; ac[0][1] = zero4; ac[1][0] = zero4; ac[1][1] = zero4;
#pragma unroll
            for (int kt = 0; kt < 24; ++kt) {
                short8 aF0 = *(const short8*)&a_ga[(kt << 9) + lane * 8];
                short8 aF1 = *(const short8*)&a_ga[((24 + kt) << 9) + lane * 8];
                short8 b0c = rg[0][kt & 3], b1c = rg[1][kt & 3];
                if (kt + 4 < 24) {
                    rg[0][kt & 3] = *(const short8*)(pB[0] + ((kt + 4) << 9));
                    rg[1][kt & 3] = *(const short8*)(pB[1] + ((kt + 4) << 9));
                }
                ac[0][0] = MFMA(aF0, b0c, ac[0][0]); ac[0][1] = MFMA(aF1, b0c, ac[0][1]);
                ac[1][0] = MFMA(aF0, b1c, ac[1][0]); ac[1][1] = MFMA(aF1, b1c, ac[1][1]);
            }
            __syncthreads();   // bar4: a_ga reads done before h / y writes
#pragma unroll
            for (int ct = 0; ct < 2; ++ct) {
                int c = ct ? c2b : c2a;
                float bhv = ct ? bh_b : bh_a;
#pragma unroll
                for (int mt = 0; mt < 2; ++mt)
#pragma unroll
                    for (int i = 0; i < 4; ++i) {
                        int row = mt * 16 + quad * 4 + i;
                        float ht = tanh_f(ac[ct][mt][i] + bhv);
                        float uu = bf2f(a3s[row * UST + c]);
                        float h  = (1.f - uu) * h32r[ct][mt][i] + uu * ht;
                        h32r[ct][mt][i] = h;
                        a_ga[aga_off(row, 256 + c)] = f2bf(h);
                    }
            }
            // y_t + zeros into cols [512,544) (tile kt=16)
            if (tid < 128) {
                int r = tid >> 2, grp = tid & 3;
                short8 v = {0, 0, 0, 0, 0, 0, 0, 0};
                if (grp == 0) {
                    const float* yp = &y_ph[((size_t)(b0 + r) * T_SZ + t) * YD];
                    v[0] = (short)f2bf(__builtin_nontemporal_load(yp));
                    v[1] = (short)f2bf(__builtin_nontemporal_load(yp + 1));
                }
                *(short8*)&a_ga[aga_off(r, 512 + grp * 8)] = v;
            }
            __syncthreads();   // bar5
        }

        // ============ stage 3 (fused): P = tanh([x,h]@Wzp), Q = tanh([x,h,y]@Wzq) ============
        {
            const u16* pP[2]; const u16* pQ[2];
            pP[0] = wts + W3_OFF + (((2 * wv    ) * 17) << 9) + lane * 8;
            pP[1] = wts + W3_OFF + (((2 * wv + 1) * 17) << 9) + lane * 8;
            pQ[0] = wts + W3_OFF + (((16 + 2 * wv    ) * 17) << 9) + lane * 8;
            pQ[1] = wts + W3_OFF + (((16 + 2 * wv + 1) * 17) << 9) + lane * 8;
            short8 rp[2][4], rq[2][4];
#pragma unroll
            for (int d = 0; d < 4; ++d) {
                rp[0][d] = *(const short8*)(pP[0] + (d << 9));
                rp[1][d] = *(const short8*)(pP[1] + (d << 9));
                rq[0][d] = *(const short8*)(pQ[0] + (d << 9));
                rq[1][d] = *(const short8*)(pQ[1] + (d << 9));
            }
            float4v aP[2][2], aQ[2][2];
            aP[0][0] = zero4; aP[0][1] = zero4; aP[1][0] = zero4; aP[1][1] = zero4;
            aQ[0][0] = zero4; aQ[0][1] = zero4; aQ[1][0] = zero4; aQ[1][1] = zero4;
#pragma unroll
            for (int kt = 0; kt < 17; ++kt) {
                short8 aF0 = *(const short8*)&a_ga[(kt << 9) + lane * 8];
                short8 aF1 = *(const short8*)&a_ga[((24 + kt) << 9) + lane * 8];
                short8 bq0 = rq[0][kt & 3], bq1 = rq[1][kt & 3];
                if (kt + 4 < 17) {
                    rq[0][kt & 3] = *(const short8*)(pQ[0] + ((kt + 4) << 9));
                    rq[1][kt & 3] = *(const short8*)(pQ[1] + ((kt + 4) << 9));
                }
                aQ[0][0] = MFMA(aF0, bq0, aQ[0][0]); aQ[0][1] = MFMA(aF1, bq0, aQ[0][1]);
                aQ[1][0] = MFMA(aF0, bq1, aQ[1][0]); aQ[1][1] = MFMA(aF1, bq1, aQ[1][1]);
                if (kt < 16) {
                    short8 bp0 = rp[0][kt & 3], bp1 = rp[1][kt & 3];
                    if (kt + 4 < 16) {
                        rp[0][kt & 3] = *(const short8*)(pP[0] + ((kt + 4) << 9));
                        rp[1][kt & 3] = *(const short8*)(pP[1] + ((kt + 4) << 9));
                    }
                    aP[0][0] = MFMA(aF0, bp0, aP[0][0]); aP[0][1] = MFMA(aF1, bp0, aP[0][1]);
                    aP[1][0] = MFMA(aF0, bp1, aP[1][0]); aP[1][1] = MFMA(aF1, bp1, aP[1][1]);
                }
            }
            if (tid < BM) kl_acc[tid] = 0.f;
            // write P,Q frags (u_bf dead since bar5 -> safe to overwrite union)
#pragma unroll
            for (int ct = 0; ct < 2; ++ct) {
                int c = ct ? c2b : c2a;
                float bzpv = ct ? bzp_b : bzp_a;
                float bzqv = ct ? bzq_b : bzq_a;
#pragma unroll
                for (int mt = 0; mt < 2; ++mt)
#pragma unroll
                    for (int i = 0; i < 4; ++i) {
                        int row = mt * 16 + quad * 4 + i;
                        a3s[a3s_off(row, c, 0)] = f2bf(tanh_f(aP[ct][mt][i] + bzpv));
                        a3s[a3s_off(row, c, 1)] = f2bf(tanh_f(aQ[ct][mt][i] + bzqv));
                    }
            }
            __syncthreads();   // bar6
        }

        // ============ stage 4 (fused 4 heads): mu/s, z_post, KL ============
        {
            float er[2][2][4];
#pragma unroll
            for (int ct = 0; ct < 2; ++ct)
#pragma unroll
                for (int mt = 0; mt < 2; ++mt)
#pragma unroll
                    for (int i = 0; i < 4; ++i) {
                        int row = mt * 16 + quad * 4 + i;
                        int c = ct ? c2b : c2a;
                        er[ct][mt][i] = __builtin_nontemporal_load(
                            &eps[((size_t)t * B_SZ + (b0 + row)) * ZD + c]);
                    }
            const u16* p4[8];
#pragma unroll
            for (int h = 0; h < 4; ++h)
#pragma unroll
                for (int ct = 0; ct < 2; ++ct)
                    p4[h * 2 + ct] = wts + W4_OFF + (((h * 16 + 2 * wv + ct) * 8) << 9) + lane * 8;
            short8 r4[8][2];
#pragma unroll
            for (int s = 0; s < 8; ++s) {
                r4[s][0] = *(const short8*)p4[s];
                r4[s][1] = *(const short8*)(p4[s] + 512);
            }
            float4v ac[8][2];   // [head*2+ct][mt]
#pragma unroll
            for (int s = 0; s < 8; ++s) { ac[s][0] = zero4; ac[s][1] = zero4; }
#pragma unroll
            for (int kt = 0; kt < 8; ++kt) {
                short8 aP0 = *(const short8*)&a3s[((     kt) << 9) + lane * 8];   // P mt0
                short8 aP1 = *(const short8*)&a3s[(( 8 + kt) << 9) + lane * 8];   // P mt1
                short8 aQ0 = *(const short8*)&a3s[((16 + kt) << 9) + lane * 8];   // Q mt0
                short8 aQ1 = *(const short8*)&a3s[((24 + kt) << 9) + lane * 8];   // Q mt1
                short8 bc[8];
#pragma unroll
                for (int s = 0; s < 8; ++s) {
                    bc[s] = r4[s][kt & 1];
                    if (kt + 2 < 8) r4[s][kt & 1] = *(const short8*)(p4[s] + ((kt + 2) << 9));
                }
                ac[0][0] = MFMA(aP0, bc[0], ac[0][0]); ac[0][1] = MFMA(aP1, bc[0], ac[0][1]);
                ac[1][0] = MFMA(aP0, bc[1], ac[1][0]); ac[1][1] = MFMA(aP1, bc[1], ac[1][1]);
                ac[2][0] = MFMA(aP0, bc[2], ac[2][0]); ac[2][1] = MFMA(aP1, bc[2], ac[2][1]);
                ac[3][0] = MFMA(aP0, bc[3], ac[3][0]); ac[3][1] = MFMA(aP1, bc[3], ac[3][1]);
                ac[4][0] = MFMA(aQ0, bc[4], ac[4][0]); ac[4][1] = MFMA(aQ1, bc[4], ac[4][1]);
                ac[5][0] = MFMA(aQ0, bc[5], ac[5][0]); ac[5][1] = MFMA(aQ1, bc[5], ac[5][1]);
                ac[6][0] = MFMA(aQ0, bc[6], ac[6][0]); ac[6][1] = MFMA(aQ1, bc[6], ac[6][1]);
                ac[7][0] = MFMA(aQ0, bc[7], ac[7][0]); ac[7][1] = MFMA(aQ1, bc[7], ac[7][1]);
            }
            float kl2[2][4];
#pragma unroll
            for (int mt = 0; mt < 2; ++mt)
#pragma unroll
                for (int i = 0; i < 4; ++i) kl2[mt][i] = 0.f;
#pragma unroll
            for (int ct = 0; ct < 2; ++ct) {
                int c = ct ? c2b : c2a;
                float vpm = ct ? bpm_b : bpm_a, vps = ct ? bps_b : bps_a;
                float vqm = ct ? bqm_b : bqm_a, vqs = ct ? bqs_b : bqs_a;
#pragma unroll
                for (int mt = 0; mt < 2; ++mt)
#pragma unroll
                    for (int i = 0; i < 4; ++i) {
                        int row = mt * 16 + quad * 4 + i;
                        float mp = ac[0 + ct][mt][i] + vpm;
                        float sp = ac[2 + ct][mt][i] + vps;
                        float mq = ac[4 + ct][mt][i] + vqm;
                        float sq = ac[6 + ct][mt][i] + vqs;
                        float zpost = mq + __expf(0.5f * sq) * er[ct][mt][i];
                        float dmu = mq - mp;
                        kl2[mt][i] += 0.5f * (sp - sq)
                                    + (__expf(sq) + dmu * dmu) * 0.5f * __expf(-sp) - 0.5f;
                        a_ga[aga_off(row, 512 + c)] = f2bf(zpost);
                    }
            }
#pragma unroll
            for (int mt = 0; mt < 2; ++mt)
#pragma unroll
                for (int i = 0; i < 4; ++i) {
                    float v = kl2[mt][i];
                    v += __shfl_xor(v, 1); v += __shfl_xor(v, 2);
                    v += __shfl_xor(v, 4); v += __shfl_xor(v, 8);
                    if (l15 == 0) atomicAdd(&kl_acc[mt * 16 + quad * 4 + i], v);
                }
            __syncthreads();   // bar7
            if ((tid & 15) == (t >> 1)) {
                float k = kl_acc[tid >> 4];
                if ((t & 1) == 0) klA = k; else klB = k;
            }
        }

        // ============ stage 5: g = tanh([x,h,z] @ Wg); y, g_T ============
        {
            // prefetch next-t x while stage 5 computes (consumed at loop top)
            if (t + 1 < T_SZ) {
                const float* xp = &x[((size_t)(b0 + sr) * T_SZ + (t + 1)) * XD + scc];
#pragma unroll
                for (int q = 0; q < 4; ++q)
                    xn[q] = __builtin_nontemporal_load((const float4v*)(xp + q * 4));
            }
            const u16* pB = wts + WG_OFF + ((wv * 24) << 9) + lane * 8;
            short8 rg[4];
#pragma unroll
            for (int d = 0; d < 4; ++d)
                rg[d] = *(const short8*)(pB + (d << 9));
            float4v a5[2];
            a5[0] = zero4; a5[1] = zero4;
#pragma unroll
            for (int kt = 0; kt < 24; ++kt) {
                short8 bc = rg[kt & 3];
                if (kt + 4 < 24) rg[kt & 3] = *(const short8*)(pB + ((kt + 4) << 9));
                short8 aF0 = *(const short8*)&a_ga[(kt << 9) + lane * 8];
                short8 aF1 = *(const short8*)&a_ga[((24 + kt) << 9) + lane * 8];
                a5[0] = MFMA(aF0, bc, a5[0]);
                a5[1] = MFMA(aF1, bc, a5[1]);
            }
#pragma unroll
            for (int mt = 0; mt < 2; ++mt)
#pragma unroll
                for (int i = 0; i < 4; ++i) {
                    int row = mt * 16 + quad * 4 + i;
                    float g = tanh_f(a5[mt][i] + bg_r);
                    if (tph_s[row] - 1 == t)
                        __builtin_nontemporal_store(g,
                            &out[YTOT + KLTOT + (size_t)(b0 + row) * GD + c5]);
                    float p0 = g * wy0, p1 = g * wy1;
                    p0 += __shfl_xor(p0, 1); p0 += __shfl_xor(p0, 2);
                    p0 += __shfl_xor(p0, 4); p0 += __shfl_xor(p0, 8);
                    p1 += __shfl_xor(p1, 1); p1 += __shfl_xor(p1, 2);
                    p1 += __shfl_xor(p1, 4); p1 += __shfl_xor(p1, 8);
                    if (l15 == 0) {
                        part[(wv * BM + row) * 2]     = p0;
                        part[(wv * BM + row) * 2 + 1] = p1;
                    }
                }
            __syncthreads();   // bar8
            if ((tid & 15) == (t >> 1)) {
                int r = tid >> 4;
                float s0 = by0, s1 = by1;
#pragma unroll
                for (int j = 0; j < NW; ++j) {
                    s0 += part[(j * BM + r) * 2];
                    s1 += part[(j * BM + r) * 2 + 1];
                }
                float mx = fmaxf(s0, s1);
                float e0 = __expf(s0 - mx), e1 = __expf(s1 - mx);
                float inv = 1.f / (e0 + e1);
                if ((t & 1) == 0) { yA0 = e0 * inv; yA1 = e1 * inv; }
                else              { yB0 = e0 * inv; yB1 = e1 * inv; }
            }
        }
    }

    // --- final coalesced flush of y and kl (owner thread tid = r*16 + t/2) ---
    {
        int r = tid >> 4, tt = tid & 15;
        float4v yv = {yA0, yA1, yB0, yB1};
        __builtin_nontemporal_store(yv,
            (float4v*)&out[((size_t)(b0 + r) * T_SZ + tt * 2) * YD]);
        float2v kv = {klA, klB};
        __builtin_nontemporal_store(kv,
            (float2v*)&out[YTOT + (size_t)(b0 + r) * T_SZ + tt * 2]);
    }
}

extern "C" void kernel_launch(void* const* d_in, const int* in_sizes, int n_in,
                              void* d_out, int out_size, void* d_ws, size_t ws_size,
                              hipStream_t stream)
{
    const float* x   = (const float*)d_in[0];
    const float* yph = (const float*)d_in[1];
    const int*   Tph = (const int*)  d_in[2];
    const float* h0  = (const float*)d_in[3];
    const float* z0  = (const float*)d_in[4];
    const float* eps = (const float*)d_in[5];
    const float* Wr  = (const float*)d_in[6];
    const float* br  = (const float*)d_in[7];
    const float* Wu  = (const float*)d_in[8];
    const float* bu  = (const float*)d_in[9];
    const float* Wh  = (const float*)d_in[10];
    const float* bh  = (const float*)d_in[11];
    const float* Wzp = (const float*)d_in[12];
    const float* bzp = (const float*)d_in[13];
    const float* Wpm = (const float*)d_in[14];
    const float* bpm = (const float*)d_in[15];
    const float* Wps = (const float*)d_in[16];
    const float* bps = (const float*)d_in[17];
    const float* Wzq = (const float*)d_in[18];
    const float* bzq = (const float*)d_in[19];
    const float* Wqm = (const float*)d_in[20];
    const float* bqm = (const float*)d_in[21];
    const float* Wqs = (const float*)d_in[22];
    const float* bqs = (const float*)d_in[23];
    const float* Wg  = (const float*)d_in[24];
    const float* bg  = (const float*)d_in[25];
    const float* Wy  = (const float*)d_in[26];
    const float* by  = (const float*)d_in[27];
    u16*   wts = (u16*)d_ws;
    float* out = (float*)d_out;

    hipLaunchKernelGGL(prep_weights, dim3((WTOT + 255) / 256), dim3(256), 0, stream,
                       Wr, Wu, Wh, Wzp, Wzq, Wpm, Wps, Wqm, Wqs, Wg, wts);
    hipLaunchKernelGGL(vrnn_all, dim3(B_SZ / BM), dim3(512), 0, stream,
                       x, yph, Tph, h0, z0, eps, br, bu, bh, bzp, bpm, bps,
                       bzq, bqm, bqs, bg, by, Wy, wts, out);
}